// Round 1
// baseline (1982.624 us; speedup 1.0000x reference)
//
#include <hip/hip_runtime.h>
#include <stdint.h>
#include <math.h>

#define N_ANCH   1000000
#define PRE_K    6000
#define POST_K   1000
#define WORDS    94            // ceil(6000/64) -> 6016 bit columns
#define HBITS    18
#define NBINS    (1<<HBITS)
#define CAP      8192
#define W_IMG    1333.0f
#define H_IMG    800.0f

// ws layout (bytes)
#define OFF_KEYS   0x000000u   // u32[1e6]  -> 4,000,000
#define OFF_HIST   0x400000u   // u32[NBINS] 1 MiB
#define OFF_CTRL   0x500000u   // [0]=cand count, [1]=cut bin
#define OFF_CAND   0x500100u   // u64[CAP] 64 KiB
#define OFF_BOXES  0x520100u   // float4[6016]  96,256 B
#define OFF_VALID  0x538000u   // u32[6016]
#define OFF_MASK   0x540000u   // u64[6016*94]  ~4.52 MB

__device__ __forceinline__ float ref_exp(float v) {
  // correctly-rounded f32 exp via double
  return (float)exp((double)v);
}

__device__ __forceinline__ void decode_box(float ax, float ay, float az, float aw,
                                           float dx, float dy, float dz, float dw,
                                           float& x1, float& y1, float& x2, float& y2,
                                           bool& valid) {
  // bit-exact replica of reference fp32 op order (no FMA contraction)
  float wa = __fsub_rn(az, ax);
  float ha = __fsub_rn(aw, ay);
  float xa = __fadd_rn(ax, __fmul_rn(0.5f, wa));
  float ya = __fadd_rn(ay, __fmul_rn(0.5f, ha));
  float x  = __fadd_rn(__fmul_rn(dx, wa), xa);
  float y  = __fadd_rn(__fmul_rn(dy, ha), ya);
  float w  = __fmul_rn(ref_exp(dz), wa);
  float h  = __fmul_rn(ref_exp(dw), ha);
  float hw = __fmul_rn(0.5f, w);
  float hh = __fmul_rn(0.5f, h);
  x1 = fminf(fmaxf(__fsub_rn(x, hw), 0.0f), W_IMG - 1.0f);
  y1 = fminf(fmaxf(__fsub_rn(y, hh), 0.0f), H_IMG - 1.0f);
  x2 = fminf(fmaxf(__fadd_rn(x, hw), 0.0f), W_IMG - 1.0f);
  y2 = fminf(fmaxf(__fadd_rn(y, hh), 0.0f), H_IMG - 1.0f);
  valid = (__fsub_rn(x2, x1) >= 16.0f) && (__fsub_rn(y2, y1) >= 16.0f);
}

// ---- K1: decode validity, score key, histogram ----
__global__ void k_score(const float4* __restrict__ anchors,
                        const float4* __restrict__ deltas,
                        const float*  __restrict__ logits,
                        uint32_t* __restrict__ keys,
                        uint32_t* __restrict__ hist) {
  int i = blockIdx.x * blockDim.x + threadIdx.x;
  if (i >= N_ANCH) return;
  float4 a = anchors[i];
  float4 d = deltas[i];
  float x1, y1, x2, y2; bool valid;
  decode_box(a.x, a.y, a.z, a.w, d.x, d.y, d.z, d.w, x1, y1, x2, y2, valid);
  uint32_t kd;
  if (valid) {
    double xd = (double)logits[i];
    float s = (float)(1.0 / (1.0 + exp(-xd)));
    uint32_t u = __float_as_uint(s);
    kd = 0x7FFFFFFFu & ~u;          // descending-score -> ascending key (s > 0 always)
  } else {
    kd = 0xFF800000u;               // key of -inf (sign set -> key = raw bits)
  }
  keys[i] = kd;
  atomicAdd(&hist[kd >> (32 - HBITS)], 1u);
}

// ---- K2: find cutoff bin (smallest bin with cumulative count >= PRE_K) ----
__global__ void __launch_bounds__(1024) k_findcut(const uint32_t* __restrict__ hist,
                                                  uint32_t* __restrict__ ctrl) {
  __shared__ uint32_t part[1024];
  int t = threadIdx.x;
  const int CH = NBINS / 1024;  // 256 contiguous bins per thread
  uint32_t s = 0;
  for (int b = 0; b < CH; b++) s += hist[t * CH + b];
  part[t] = s;
  __syncthreads();
  uint32_t inc = s;
  for (int off = 1; off < 1024; off <<= 1) {
    uint32_t u = (t >= off) ? part[t - off] : 0u;
    __syncthreads();
    inc += u;
    part[t] = inc;
    __syncthreads();
  }
  uint32_t ex = inc - s;
  if (ex < PRE_K && inc >= PRE_K) {  // this thread's chunk contains the crossing
    uint32_t run = ex;
    uint32_t cut = NBINS - 1;
    for (int b = 0; b < CH; b++) {
      uint32_t c = hist[t * CH + b];
      if (run + c >= PRE_K) { cut = t * CH + b; break; }
      run += c;
    }
    ctrl[1] = cut;
  }
  if (t == 1023 && inc < PRE_K) ctrl[1] = NBINS - 1;  // fewer than PRE_K total
}

// ---- K3: compact candidates (all elements in bins <= cut) ----
__global__ void k_compact(const uint32_t* __restrict__ keys,
                          const uint32_t* __restrict__ ctrl,
                          uint32_t* __restrict__ cnt,
                          uint64_t* __restrict__ cand) {
  int i = blockIdx.x * blockDim.x + threadIdx.x;
  if (i >= N_ANCH) return;
  uint32_t cut = ctrl[1];
  uint32_t k = keys[i];
  if ((k >> (32 - HBITS)) <= cut) {
    uint32_t p = atomicAdd(cnt, 1u);
    if (p < CAP) cand[p] = ((uint64_t)k << 32) | (uint32_t)i;
  }
}

// ---- K4: single-block bitonic sort of candidates (ascending key64) ----
__global__ void __launch_bounds__(1024) k_sort(const uint32_t* __restrict__ ctrl,
                                               uint64_t* __restrict__ cand) {
  __shared__ uint64_t s[CAP];   // 64 KiB
  uint32_t M = ctrl[0];
  if (M > CAP) M = CAP;
  for (int i = threadIdx.x; i < CAP; i += 1024)
    s[i] = (i < (int)M) ? cand[i] : ~0ull;
  __syncthreads();
  for (int k = 2; k <= CAP; k <<= 1) {
    for (int j = k >> 1; j > 0; j >>= 1) {
      for (int t = threadIdx.x; t < CAP; t += 1024) {
        int ixj = t ^ j;
        if (ixj > t) {
          bool up = ((t & k) == 0);
          uint64_t va = s[t], vb = s[ixj];
          if ((va > vb) == up) { s[t] = vb; s[ixj] = va; }
        }
      }
      __syncthreads();
    }
  }
  for (int i = threadIdx.x; i < PRE_K; i += 1024) cand[i] = s[i];
}

// ---- K4b: gather/re-decode top-PRE_K boxes ----
__global__ void k_gather(const uint64_t* __restrict__ sorted,
                         const float4* __restrict__ anchors,
                         const float4* __restrict__ deltas,
                         float4* __restrict__ boxes,
                         uint32_t* __restrict__ valid) {
  int r = blockIdx.x * blockDim.x + threadIdx.x;
  if (r >= WORDS * 64) return;                 // 6016 rows (padded)
  if (r >= PRE_K) { boxes[r] = make_float4(0.f, 0.f, 0.f, 0.f); valid[r] = 0u; return; }
  uint64_t kk = sorted[r];
  uint32_t kd = (uint32_t)(kk >> 32);
  if (kd >= 0xFF800000u) {                     // -inf score or pad
    boxes[r] = make_float4(0.f, 0.f, 0.f, 0.f); valid[r] = 0u; return;
  }
  uint32_t idx = (uint32_t)kk;
  float4 a = anchors[idx];
  float4 d = deltas[idx];
  float x1, y1, x2, y2; bool v;
  decode_box(a.x, a.y, a.z, a.w, d.x, d.y, d.z, d.w, x1, y1, x2, y2, v);
  boxes[r] = make_float4(x1, y1, x2, y2);
  valid[r] = 1u;
}

// ---- K5: IoU bitmask matrix (upper triangle blocks only) ----
__global__ void __launch_bounds__(64) k_iou(const float4* __restrict__ boxes,
                                            uint64_t* __restrict__ mask) {
  int by = blockIdx.y, bx = blockIdx.x;
  if (bx < by) return;
  __shared__ float4 cb[64];
  int t = threadIdx.x;
  cb[t] = boxes[bx * 64 + t];
  __syncthreads();
  int i = by * 64 + t;
  float4 b = boxes[i];
  float ax1 = b.x, ay1 = b.y, ax2 = b.z, ay2 = b.w;
  float areaA = __fmul_rn(__fsub_rn(ax2, ax1), __fsub_rn(ay2, ay1));
  uint64_t bits = 0;
  for (int c = 0; c < 64; c++) {
    float4 o = cb[c];
    float areaB = __fmul_rn(__fsub_rn(o.z, o.x), __fsub_rn(o.w, o.y));
    float ix1 = fmaxf(ax1, o.x), iy1 = fmaxf(ay1, o.y);
    float ix2 = fminf(ax2, o.z), iy2 = fminf(ay2, o.w);
    float iw = fmaxf(__fsub_rn(ix2, ix1), 0.0f);
    float ih = fmaxf(__fsub_rn(iy2, iy1), 0.0f);
    float inter = __fmul_rn(iw, ih);
    float uni = __fsub_rn(__fadd_rn(areaA, areaB), inter);
    bool sup = (uni > 0.0f) && (__fdiv_rn(inter, uni) > 0.7f);
    bits |= ((uint64_t)sup) << c;
  }
  mask[(size_t)i * WORDS + bx] = bits;
}

// ---- K6: sequential NMS scan, single wave ----
__global__ void __launch_bounds__(64) k_nms(const uint64_t* __restrict__ mask,
                                            const float4* __restrict__ boxes,
                                            const uint32_t* __restrict__ valid,
                                            float* __restrict__ out) {
  int lane = threadIdx.x;
  uint64_t r0 = 0, r1 = 0;   // removed-bit words: lane owns word lane and lane+64
  int cnt = 0;
  for (int g = 0; g < WORDS && cnt < POST_K; g++) {
    int base = g * 64;
    int nrow = PRE_K - base; if (nrow > 64) nrow = 64;
    if (nrow <= 0) break;
    uint64_t cur = (g < 64) ? __shfl(r0, g) : __shfl(r1, g - 64);
    uint64_t colv = 0;
    if (lane < nrow) colv = mask[(size_t)(base + lane) * WORDS + g];
    uint32_t vf = (lane < nrow) ? valid[base + lane] : 0u;
    uint64_t vmask = __ballot(vf != 0u);
    uint64_t keptmask = 0;
    for (int r = 0; r < nrow; r++) {
      bool kept = ((vmask >> r) & 1ull) && !((cur >> r) & 1ull);
      if (kept) {
        int i = base + r;
        if (lane < 4) out[(size_t)cnt * 4 + lane] = ((const float*)boxes)[(size_t)i * 4 + lane];
        cnt++;
        keptmask |= 1ull << r;
        if (cnt >= POST_K) break;
        uint64_t m = __shfl(colv, r);
        if (r < 63) cur |= (m & (~0ull << (r + 1)));
      }
    }
    // fold kept rows' suppression into later words (w > g only)
    uint64_t km = keptmask;
    while (km) {
      int r = __ffsll((unsigned long long)km) - 1;
      km &= km - 1;
      const uint64_t* row = mask + (size_t)(base + r) * WORDS;
      if (lane > g) r0 |= row[lane];
      int w1 = lane + 64;
      if (w1 < WORDS && w1 > g) r1 |= row[w1];
    }
  }
}

extern "C" void kernel_launch(void* const* d_in, const int* in_sizes, int n_in,
                              void* d_out, int out_size, void* d_ws, size_t ws_size,
                              hipStream_t stream) {
  const float4* anchors = (const float4*)d_in[1];
  const float4* deltas  = (const float4*)d_in[2];
  const float*  logits  = (const float*)d_in[3];
  char* w = (char*)d_ws;
  uint32_t* keys  = (uint32_t*)(w + OFF_KEYS);
  uint32_t* hist  = (uint32_t*)(w + OFF_HIST);
  uint32_t* ctrl  = (uint32_t*)(w + OFF_CTRL);
  uint64_t* cand  = (uint64_t*)(w + OFF_CAND);
  float4*   boxes = (float4*)(w + OFF_BOXES);
  uint32_t* valid = (uint32_t*)(w + OFF_VALID);
  uint64_t* mask  = (uint64_t*)(w + OFF_MASK);
  float*    out   = (float*)d_out;

  // zero hist + ctrl, zero output (harness poisons ws/out before every timed call)
  hipMemsetAsync(w + OFF_HIST, 0, (size_t)NBINS * 4 + 256, stream);
  hipMemsetAsync(d_out, 0, (size_t)out_size * sizeof(float), stream);

  int blocks = (N_ANCH + 255) / 256;
  k_score<<<blocks, 256, 0, stream>>>(anchors, deltas, logits, keys, hist);
  k_findcut<<<1, 1024, 0, stream>>>(hist, ctrl);
  k_compact<<<blocks, 256, 0, stream>>>(keys, ctrl, &ctrl[0], cand);
  k_sort<<<1, 1024, 0, stream>>>(ctrl, cand);
  k_gather<<<(WORDS * 64 + 255) / 256, 256, 0, stream>>>(cand, anchors, deltas, boxes, valid);
  k_iou<<<dim3(WORDS, WORDS), 64, 0, stream>>>(boxes, mask);
  k_nms<<<1, 64, 0, stream>>>(mask, boxes, valid, out);
}

// Round 2
// 1287.850 us; speedup vs baseline: 1.5395x; 1.5395x over previous
//
#include <hip/hip_runtime.h>
#include <stdint.h>
#include <math.h>

#define N_ANCH   1000000
#define PRE_K    6000
#define POST_K   1000
#define WORDS    94            // ceil(6000/64) -> 6016 bit columns
#define ROWS     6016          // WORDS*64
#define HBITS    18
#define NBINS    (1<<HBITS)
#define CAP      8192
#define W_IMG    1333.0f
#define H_IMG    800.0f

// ws layout (bytes)
#define OFF_KEYS   0x000000u   // u32[1e6]  -> 4,000,000
#define OFF_HIST   0x400000u   // u32[NBINS] 1 MiB
#define OFF_CTRL   0x500000u   // [0]=cand count, [1]=cut bin
#define OFF_CAND   0x500100u   // u64[CAP] 64 KiB
#define OFF_BOXES  0x520100u   // float4[6016]  96,256 B
#define OFF_VALID  0x538000u   // u32[6016]
#define OFF_MASK   0x540000u   // u64[94*6016] transposed: maskT[w*ROWS + row]

__device__ __forceinline__ float ref_exp(float v) {
  // correctly-rounded f32 exp via double
  return (float)exp((double)v);
}

__device__ __forceinline__ void decode_box(float ax, float ay, float az, float aw,
                                           float dx, float dy, float dz, float dw,
                                           float& x1, float& y1, float& x2, float& y2,
                                           bool& valid) {
  // bit-exact replica of reference fp32 op order (no FMA contraction)
  float wa = __fsub_rn(az, ax);
  float ha = __fsub_rn(aw, ay);
  float xa = __fadd_rn(ax, __fmul_rn(0.5f, wa));
  float ya = __fadd_rn(ay, __fmul_rn(0.5f, ha));
  float x  = __fadd_rn(__fmul_rn(dx, wa), xa);
  float y  = __fadd_rn(__fmul_rn(dy, ha), ya);
  float w  = __fmul_rn(ref_exp(dz), wa);
  float h  = __fmul_rn(ref_exp(dw), ha);
  float hw = __fmul_rn(0.5f, w);
  float hh = __fmul_rn(0.5f, h);
  x1 = fminf(fmaxf(__fsub_rn(x, hw), 0.0f), W_IMG - 1.0f);
  y1 = fminf(fmaxf(__fsub_rn(y, hh), 0.0f), H_IMG - 1.0f);
  x2 = fminf(fmaxf(__fadd_rn(x, hw), 0.0f), W_IMG - 1.0f);
  y2 = fminf(fmaxf(__fadd_rn(y, hh), 0.0f), H_IMG - 1.0f);
  valid = (__fsub_rn(x2, x1) >= 16.0f) && (__fsub_rn(y2, y1) >= 16.0f);
}

// ---- K1: decode validity, score key, histogram ----
__global__ void k_score(const float4* __restrict__ anchors,
                        const float4* __restrict__ deltas,
                        const float*  __restrict__ logits,
                        uint32_t* __restrict__ keys,
                        uint32_t* __restrict__ hist) {
  int i = blockIdx.x * blockDim.x + threadIdx.x;
  if (i >= N_ANCH) return;
  float4 a = anchors[i];
  float4 d = deltas[i];
  float x1, y1, x2, y2; bool valid;
  decode_box(a.x, a.y, a.z, a.w, d.x, d.y, d.z, d.w, x1, y1, x2, y2, valid);
  uint32_t kd;
  if (valid) {
    double xd = (double)logits[i];
    float s = (float)(1.0 / (1.0 + exp(-xd)));
    uint32_t u = __float_as_uint(s);
    kd = 0x7FFFFFFFu & ~u;          // descending-score -> ascending key (s > 0 always)
  } else {
    kd = 0xFF800000u;               // key of -inf (sign set -> key = raw bits)
  }
  keys[i] = kd;
  atomicAdd(&hist[kd >> (32 - HBITS)], 1u);
}

// ---- K2: find cutoff bin (smallest bin with cumulative count >= PRE_K) ----
__global__ void __launch_bounds__(1024) k_findcut(const uint32_t* __restrict__ hist,
                                                  uint32_t* __restrict__ ctrl) {
  __shared__ uint32_t part[1024];
  int t = threadIdx.x;
  const int CH = NBINS / 1024;  // 256 contiguous bins per thread
  uint32_t s = 0;
  for (int b = 0; b < CH; b++) s += hist[t * CH + b];
  part[t] = s;
  __syncthreads();
  uint32_t inc = s;
  for (int off = 1; off < 1024; off <<= 1) {
    uint32_t u = (t >= off) ? part[t - off] : 0u;
    __syncthreads();
    inc += u;
    part[t] = inc;
    __syncthreads();
  }
  uint32_t ex = inc - s;
  if (ex < PRE_K && inc >= PRE_K) {  // this thread's chunk contains the crossing
    uint32_t run = ex;
    uint32_t cut = NBINS - 1;
    for (int b = 0; b < CH; b++) {
      uint32_t c = hist[t * CH + b];
      if (run + c >= PRE_K) { cut = t * CH + b; break; }
      run += c;
    }
    ctrl[1] = cut;
  }
  if (t == 1023 && inc < PRE_K) ctrl[1] = NBINS - 1;  // fewer than PRE_K total
}

// ---- K3: compact candidates (all elements in bins <= cut) ----
__global__ void k_compact(const uint32_t* __restrict__ keys,
                          const uint32_t* __restrict__ ctrl,
                          uint32_t* __restrict__ cnt,
                          uint64_t* __restrict__ cand) {
  int i = blockIdx.x * blockDim.x + threadIdx.x;
  if (i >= N_ANCH) return;
  uint32_t cut = ctrl[1];
  uint32_t k = keys[i];
  if ((k >> (32 - HBITS)) <= cut) {
    uint32_t p = atomicAdd(cnt, 1u);
    if (p < CAP) cand[p] = ((uint64_t)k << 32) | (uint32_t)i;
  }
}

// ---- K4: single-block bitonic sort of candidates (ascending key64) ----
__global__ void __launch_bounds__(1024) k_sort(const uint32_t* __restrict__ ctrl,
                                               uint64_t* __restrict__ cand) {
  __shared__ uint64_t s[CAP];   // 64 KiB
  uint32_t M = ctrl[0];
  if (M > CAP) M = CAP;
  for (int i = threadIdx.x; i < CAP; i += 1024)
    s[i] = (i < (int)M) ? cand[i] : ~0ull;
  __syncthreads();
  for (int k = 2; k <= CAP; k <<= 1) {
    for (int j = k >> 1; j > 0; j >>= 1) {
      for (int t = threadIdx.x; t < CAP; t += 1024) {
        int ixj = t ^ j;
        if (ixj > t) {
          bool up = ((t & k) == 0);
          uint64_t va = s[t], vb = s[ixj];
          if ((va > vb) == up) { s[t] = vb; s[ixj] = va; }
        }
      }
      __syncthreads();
    }
  }
  for (int i = threadIdx.x; i < PRE_K; i += 1024) cand[i] = s[i];
}

// ---- K4b: gather/re-decode top-PRE_K boxes ----
__global__ void k_gather(const uint64_t* __restrict__ sorted,
                         const float4* __restrict__ anchors,
                         const float4* __restrict__ deltas,
                         float4* __restrict__ boxes,
                         uint32_t* __restrict__ valid) {
  int r = blockIdx.x * blockDim.x + threadIdx.x;
  if (r >= ROWS) return;                       // 6016 rows (padded)
  if (r >= PRE_K) { boxes[r] = make_float4(0.f, 0.f, 0.f, 0.f); valid[r] = 0u; return; }
  uint64_t kk = sorted[r];
  uint32_t kd = (uint32_t)(kk >> 32);
  if (kd >= 0xFF800000u) {                     // -inf score or pad
    boxes[r] = make_float4(0.f, 0.f, 0.f, 0.f); valid[r] = 0u; return;
  }
  uint32_t idx = (uint32_t)kk;
  float4 a = anchors[idx];
  float4 d = deltas[idx];
  float x1, y1, x2, y2; bool v;
  decode_box(a.x, a.y, a.z, a.w, d.x, d.y, d.z, d.w, x1, y1, x2, y2, v);
  boxes[r] = make_float4(x1, y1, x2, y2);
  valid[r] = 1u;
}

// ---- K5: IoU bitmask matrix, TRANSPOSED layout maskT[w*ROWS + row] ----
__global__ void __launch_bounds__(64) k_iou(const float4* __restrict__ boxes,
                                            uint64_t* __restrict__ maskT) {
  int by = blockIdx.y, bx = blockIdx.x;
  if (bx < by) return;               // only rows <= column-group matter for NMS
  __shared__ float4 cb[64];
  int t = threadIdx.x;
  cb[t] = boxes[bx * 64 + t];
  __syncthreads();
  int i = by * 64 + t;
  float4 b = boxes[i];
  float ax1 = b.x, ay1 = b.y, ax2 = b.z, ay2 = b.w;
  float areaA = __fmul_rn(__fsub_rn(ax2, ax1), __fsub_rn(ay2, ay1));
  uint64_t bits = 0;
  for (int c = 0; c < 64; c++) {
    float4 o = cb[c];
    float areaB = __fmul_rn(__fsub_rn(o.z, o.x), __fsub_rn(o.w, o.y));
    float ix1 = fmaxf(ax1, o.x), iy1 = fmaxf(ay1, o.y);
    float ix2 = fminf(ax2, o.z), iy2 = fminf(ay2, o.w);
    float iw = fmaxf(__fsub_rn(ix2, ix1), 0.0f);
    float ih = fmaxf(__fsub_rn(iy2, iy1), 0.0f);
    float inter = __fmul_rn(iw, ih);
    float uni = __fsub_rn(__fadd_rn(areaA, areaB), inter);
    bool sup = (uni > 0.0f) && (__fdiv_rn(inter, uni) > 0.7f);
    bits |= ((uint64_t)sup) << c;
  }
  maskT[(size_t)bx * ROWS + i] = bits;   // lanes i contiguous -> 512B coalesced
}

// wave-uniform 64-bit broadcast via v_readlane (lane idx must be uniform)
__device__ __forceinline__ uint64_t bcast64(uint64_t v, int lane) {
  uint32_t lo = (uint32_t)__builtin_amdgcn_readlane((int)(uint32_t)v, lane);
  uint32_t hi = (uint32_t)__builtin_amdgcn_readlane((int)(uint32_t)(v >> 32), lane);
  return ((uint64_t)hi << 32) | lo;
}

// select-OR 64 contiguous rows' words by keptmask (32 independent 16B loads)
__device__ __forceinline__ uint64_t fold_sel(const uint64_t* rowbase, uint64_t keptmask) {
  const ulonglong2* p = (const ulonglong2*)rowbase;
  uint64_t acc = 0;
  #pragma unroll
  for (int rr = 0; rr < 32; rr++) {
    ulonglong2 m2 = p[rr];
    acc |= (m2.x & (0ull - ((keptmask >> (2 * rr)) & 1ull)));
    acc |= (m2.y & (0ull - ((keptmask >> (2 * rr + 1)) & 1ull)));
  }
  return acc;
}

// ---- K6: sequential NMS scan, single wave, pipelined fold ----
__global__ void __launch_bounds__(64) k_nms(const uint64_t* __restrict__ maskT,
                                            const float4* __restrict__ boxes,
                                            const uint32_t* __restrict__ valid,
                                            float* __restrict__ out) {
  __shared__ uint32_t list[POST_K];
  int lane = threadIdx.x;
  int w0 = lane, w1 = lane + 64;
  uint64_t r0 = 0, r1 = 0;   // removed-bit words: lane owns words w0, w1
  int cnt = 0;
  for (int g = 0; g < WORDS && cnt < POST_K; g++) {
    int base = g * 64;
    uint64_t cur = (g < 64) ? bcast64(r0, g) : bcast64(r1, g - 64);
    uint64_t colv = maskT[(size_t)g * ROWS + base + lane];  // row (base+lane)'s word g
    uint32_t vf = valid[base + lane];
    uint64_t vmask = __ballot(vf != 0u);
    uint64_t alive = vmask & ~cur;     // uniform across lanes
    uint64_t keptmask = 0;
    while (alive) {
      int r = __ffsll((unsigned long long)alive) - 1;   // next kept row
      keptmask |= 1ull << r;
      if (lane == 0) list[cnt] = (uint32_t)(base + r);
      cnt++;
      if (cnt >= POST_K) break;
      uint64_t m = bcast64(colv, r);   // row r's suppression bits within this word
      alive &= ~m;
      alive &= ~(1ull << r);
    }
    if (keptmask && cnt < POST_K) {
      if (w0 > g)
        r0 |= fold_sel(maskT + (size_t)w0 * ROWS + base, keptmask);
      if (w1 > g && w1 < WORDS)
        r1 |= fold_sel(maskT + (size_t)w1 * ROWS + base, keptmask);
    }
  }
  __syncthreads();
  float4* outv = (float4*)out;
  for (int k = lane; k < cnt; k += 64)
    outv[k] = boxes[list[k]];
}

extern "C" void kernel_launch(void* const* d_in, const int* in_sizes, int n_in,
                              void* d_out, int out_size, void* d_ws, size_t ws_size,
                              hipStream_t stream) {
  const float4* anchors = (const float4*)d_in[1];
  const float4* deltas  = (const float4*)d_in[2];
  const float*  logits  = (const float*)d_in[3];
  char* w = (char*)d_ws;
  uint32_t* keys  = (uint32_t*)(w + OFF_KEYS);
  uint32_t* hist  = (uint32_t*)(w + OFF_HIST);
  uint32_t* ctrl  = (uint32_t*)(w + OFF_CTRL);
  uint64_t* cand  = (uint64_t*)(w + OFF_CAND);
  float4*   boxes = (float4*)(w + OFF_BOXES);
  uint32_t* valid = (uint32_t*)(w + OFF_VALID);
  uint64_t* maskT = (uint64_t*)(w + OFF_MASK);
  float*    out   = (float*)d_out;

  // zero hist + ctrl, zero output (harness poisons ws/out before every timed call)
  hipMemsetAsync(w + OFF_HIST, 0, (size_t)NBINS * 4 + 256, stream);
  hipMemsetAsync(d_out, 0, (size_t)out_size * sizeof(float), stream);

  int blocks = (N_ANCH + 255) / 256;
  k_score<<<blocks, 256, 0, stream>>>(anchors, deltas, logits, keys, hist);
  k_findcut<<<1, 1024, 0, stream>>>(hist, ctrl);
  k_compact<<<blocks, 256, 0, stream>>>(keys, ctrl, &ctrl[0], cand);
  k_sort<<<1, 1024, 0, stream>>>(ctrl, cand);
  k_gather<<<(ROWS + 255) / 256, 256, 0, stream>>>(cand, anchors, deltas, boxes, valid);
  k_iou<<<dim3(WORDS, WORDS), 64, 0, stream>>>(boxes, maskT);
  k_nms<<<1, 64, 0, stream>>>(maskT, boxes, valid, out);
}

// Round 3
// 463.031 us; speedup vs baseline: 4.2818x; 2.7813x over previous
//
#include <hip/hip_runtime.h>
#include <stdint.h>
#include <math.h>

#define N_ANCH   1000000
#define PRE_K    6000
#define POST_K   1000
#define WORDS    94            // ceil(6000/64) -> 6016 bit columns
#define ROWS     6016          // WORDS*64
#define CAP      8192
#define W_IMG    1333.0f
#define H_IMG    800.0f
#define NBLK1    64            // histogram blocks (x1024 threads)

// ws layout (bytes)
#define OFF_KEYS   0x000000u   // u32[1e6]  -> 4,000,000
#define OFF_PART1  0x400000u   // u32[NBLK1*4096] = 1 MiB
#define OFF_PART2  0x500000u   // u32[NBLK1*256]  = 64 KiB
#define OFF_CTRL   0x510000u   // [0]=cand count [1]=T20 [2]=coarse bin c [3]=base
#define OFF_CAND   0x510100u   // u64[CAP] 64 KiB
#define OFF_BOXES  0x531000u   // float4[6016]  96,256 B
#define OFF_VALID  0x549000u   // u32[6016]
#define OFF_MASK   0x550000u   // u64[94*6016] transposed: maskT[w*ROWS + row]

__device__ __forceinline__ float ref_exp(float v) {
  return (float)exp((double)v);   // correctly-rounded f32 exp via double
}

__device__ __forceinline__ void decode_box(float ax, float ay, float az, float aw,
                                           float dx, float dy, float dz, float dw,
                                           float& x1, float& y1, float& x2, float& y2,
                                           bool& valid) {
  // bit-exact replica of reference fp32 op order (no FMA contraction)
  float wa = __fsub_rn(az, ax);
  float ha = __fsub_rn(aw, ay);
  float xa = __fadd_rn(ax, __fmul_rn(0.5f, wa));
  float ya = __fadd_rn(ay, __fmul_rn(0.5f, ha));
  float x  = __fadd_rn(__fmul_rn(dx, wa), xa);
  float y  = __fadd_rn(__fmul_rn(dy, ha), ya);
  float w  = __fmul_rn(ref_exp(dz), wa);
  float h  = __fmul_rn(ref_exp(dw), ha);
  float hw = __fmul_rn(0.5f, w);
  float hh = __fmul_rn(0.5f, h);
  x1 = fminf(fmaxf(__fsub_rn(x, hw), 0.0f), W_IMG - 1.0f);
  y1 = fminf(fmaxf(__fsub_rn(y, hh), 0.0f), H_IMG - 1.0f);
  x2 = fminf(fmaxf(__fadd_rn(x, hw), 0.0f), W_IMG - 1.0f);
  y2 = fminf(fmaxf(__fadd_rn(y, hh), 0.0f), H_IMG - 1.0f);
  valid = (__fsub_rn(x2, x1) >= 16.0f) && (__fsub_rn(y2, y1) >= 16.0f);
}

// ---- K1: decode validity, score key, per-block LDS 12-bit histogram ----
__global__ void __launch_bounds__(1024) k_score(const float4* __restrict__ anchors,
                                                const float4* __restrict__ deltas,
                                                const float*  __restrict__ logits,
                                                uint32_t* __restrict__ keys,
                                                uint32_t* __restrict__ part1) {
  __shared__ uint32_t lh[4096];
  int tid = threadIdx.x;
  for (int b = tid; b < 4096; b += 1024) lh[b] = 0u;
  __syncthreads();
  for (int i = blockIdx.x * 1024 + tid; i < N_ANCH; i += NBLK1 * 1024) {
    float4 a = anchors[i];
    float4 d = deltas[i];
    float x1, y1, x2, y2; bool valid;
    decode_box(a.x, a.y, a.z, a.w, d.x, d.y, d.z, d.w, x1, y1, x2, y2, valid);
    uint32_t kd;
    if (valid) {
      double xd = (double)logits[i];
      float s = (float)(1.0 / (1.0 + exp(-xd)));
      uint32_t u = __float_as_uint(s);
      kd = 0x7FFFFFFFu & ~u;        // descending-score -> ascending key
    } else {
      kd = 0xFF800000u;             // -inf key (bin 4088, above all valid bins)
    }
    keys[i] = kd;
    atomicAdd(&lh[kd >> 20], 1u);   // LDS atomic, block-private
  }
  __syncthreads();
  for (int b = tid; b < 4096; b += 1024)
    part1[blockIdx.x * 4096 + b] = lh[b];
}

// ---- K2a: reduce partials + find coarse 12-bit cut bin ----
__global__ void __launch_bounds__(1024) k_findcut1(const uint32_t* __restrict__ part1,
                                                   uint32_t* __restrict__ ctrl) {
  __shared__ uint32_t part[1024];
  int t = threadIdx.x;
  uint4 s4 = make_uint4(0u, 0u, 0u, 0u);     // thread t owns bins 4t..4t+3
  const uint4* p4 = (const uint4*)part1;
  for (int k = 0; k < NBLK1; k++) {
    uint4 q = p4[k * 1024 + t];
    s4.x += q.x; s4.y += q.y; s4.z += q.z; s4.w += q.w;
  }
  uint32_t tot = s4.x + s4.y + s4.z + s4.w;
  part[t] = tot;
  __syncthreads();
  uint32_t inc = tot;
  for (int off = 1; off < 1024; off <<= 1) {
    uint32_t u = (t >= off) ? part[t - off] : 0u;
    __syncthreads();
    inc += u;
    part[t] = inc;
    __syncthreads();
  }
  uint32_t ex = inc - tot;
  if (ex < PRE_K && inc >= PRE_K) {          // crossing inside this thread's 4 bins
    uint32_t run = ex;
    uint32_t binv[4] = { s4.x, s4.y, s4.z, s4.w };
    for (int b = 0; b < 4; b++) {
      if (run + binv[b] >= PRE_K) { ctrl[2] = 4 * t + b; ctrl[3] = run; break; }
      run += binv[b];
    }
  }
  if (t == 1023 && inc < PRE_K) { ctrl[2] = 4095u; ctrl[3] = inc; }
}

// ---- K2b: refine histogram — next 8 bits inside coarse bin c ----
__global__ void __launch_bounds__(1024) k_hist2(const uint32_t* __restrict__ keys,
                                                const uint32_t* __restrict__ ctrl,
                                                uint32_t* __restrict__ part2) {
  __shared__ uint32_t lh[256];
  int tid = threadIdx.x;
  if (tid < 256) lh[tid] = 0u;
  __syncthreads();
  uint32_t c = ctrl[2];
  for (int i = blockIdx.x * 1024 + tid; i < N_ANCH; i += NBLK1 * 1024) {
    uint32_t k = keys[i];
    if ((k >> 20) == c) atomicAdd(&lh[(k >> 12) & 0xFFu], 1u);
  }
  __syncthreads();
  if (tid < 256) part2[blockIdx.x * 256 + tid] = lh[tid];
}

// ---- K2c: reduce + find final 20-bit threshold T ----
__global__ void __launch_bounds__(256) k_findcut2(const uint32_t* __restrict__ part2,
                                                  uint32_t* __restrict__ ctrl) {
  __shared__ uint32_t part[256];
  int t = threadIdx.x;
  uint32_t s = 0;
  for (int k = 0; k < NBLK1; k++) s += part2[k * 256 + t];
  part[t] = s;
  __syncthreads();
  uint32_t inc = s;
  for (int off = 1; off < 256; off <<= 1) {
    uint32_t u = (t >= off) ? part[t - off] : 0u;
    __syncthreads();
    inc += u;
    part[t] = inc;
    __syncthreads();
  }
  uint32_t base = ctrl[3];
  uint32_t ex = inc - s;
  if (base + ex < PRE_K && base + inc >= PRE_K)
    ctrl[1] = (ctrl[2] << 8) | (uint32_t)t;          // T20
  if (t == 255 && base + inc < PRE_K)
    ctrl[1] = 0xFFFFFu;                              // fallback: take everything
}

// ---- K3: compact candidates (key prefix <= T), wave-aggregated atomic ----
__global__ void k_compact(const uint32_t* __restrict__ keys,
                          const uint32_t* __restrict__ ctrl,
                          uint32_t* __restrict__ cnt,
                          uint64_t* __restrict__ cand) {
  int i = blockIdx.x * blockDim.x + threadIdx.x;
  uint32_t T = ctrl[1];
  bool pass = (i < N_ANCH) && ((keys[i] >> 12) <= T);
  uint64_t m = __ballot(pass);
  if (pass) {
    int lane = threadIdx.x & 63;
    int leader = __ffsll((unsigned long long)m) - 1;
    uint32_t base = 0;
    if (lane == leader) base = atomicAdd(cnt, (uint32_t)__popcll((unsigned long long)m));
    base = (uint32_t)__shfl((int)base, leader);
    uint32_t pos = (uint32_t)__popcll((unsigned long long)(m & ((1ull << lane) - 1ull)));
    uint32_t p = base + pos;
    if (p < CAP) cand[p] = ((uint64_t)keys[i] << 32) | (uint32_t)i;
  }
}

// ---- K4: single-block bitonic sort of candidates (ascending key64) ----
__global__ void __launch_bounds__(1024) k_sort(const uint32_t* __restrict__ ctrl,
                                               uint64_t* __restrict__ cand) {
  __shared__ uint64_t s[CAP];   // 64 KiB
  uint32_t M = ctrl[0];
  if (M > CAP) M = CAP;
  for (int i = threadIdx.x; i < CAP; i += 1024)
    s[i] = (i < (int)M) ? cand[i] : ~0ull;
  __syncthreads();
  for (int k = 2; k <= CAP; k <<= 1) {
    for (int j = k >> 1; j > 0; j >>= 1) {
      for (int t = threadIdx.x; t < CAP; t += 1024) {
        int ixj = t ^ j;
        if (ixj > t) {
          bool up = ((t & k) == 0);
          uint64_t va = s[t], vb = s[ixj];
          if ((va > vb) == up) { s[t] = vb; s[ixj] = va; }
        }
      }
      __syncthreads();
    }
  }
  for (int i = threadIdx.x; i < PRE_K; i += 1024) cand[i] = s[i];
}

// ---- K4b: gather/re-decode top-PRE_K boxes ----
__global__ void k_gather(const uint64_t* __restrict__ sorted,
                         const float4* __restrict__ anchors,
                         const float4* __restrict__ deltas,
                         float4* __restrict__ boxes,
                         uint32_t* __restrict__ valid) {
  int r = blockIdx.x * blockDim.x + threadIdx.x;
  if (r >= ROWS) return;
  if (r >= PRE_K) { boxes[r] = make_float4(0.f, 0.f, 0.f, 0.f); valid[r] = 0u; return; }
  uint64_t kk = sorted[r];
  uint32_t kd = (uint32_t)(kk >> 32);
  if (kd >= 0xFF800000u) {                     // -inf score or pad
    boxes[r] = make_float4(0.f, 0.f, 0.f, 0.f); valid[r] = 0u; return;
  }
  uint32_t idx = (uint32_t)kk;
  float4 a = anchors[idx];
  float4 d = deltas[idx];
  float x1, y1, x2, y2; bool v;
  decode_box(a.x, a.y, a.z, a.w, d.x, d.y, d.z, d.w, x1, y1, x2, y2, v);
  boxes[r] = make_float4(x1, y1, x2, y2);
  valid[r] = 1u;
}

// ---- K5: IoU bitmask matrix, TRANSPOSED layout maskT[w*ROWS + row] ----
__global__ void __launch_bounds__(64) k_iou(const float4* __restrict__ boxes,
                                            uint64_t* __restrict__ maskT) {
  int by = blockIdx.y, bx = blockIdx.x;
  if (bx < by) return;               // only upper-triangle word blocks needed
  __shared__ float4 cb[64];
  int t = threadIdx.x;
  cb[t] = boxes[bx * 64 + t];
  __syncthreads();
  int i = by * 64 + t;
  float4 b = boxes[i];
  float ax1 = b.x, ay1 = b.y, ax2 = b.z, ay2 = b.w;
  float areaA = __fmul_rn(__fsub_rn(ax2, ax1), __fsub_rn(ay2, ay1));
  uint64_t bits = 0;
  for (int c = 0; c < 64; c++) {
    float4 o = cb[c];
    float areaB = __fmul_rn(__fsub_rn(o.z, o.x), __fsub_rn(o.w, o.y));
    float ix1 = fmaxf(ax1, o.x), iy1 = fmaxf(ay1, o.y);
    float ix2 = fminf(ax2, o.z), iy2 = fminf(ay2, o.w);
    float iw = fmaxf(__fsub_rn(ix2, ix1), 0.0f);
    float ih = fmaxf(__fsub_rn(iy2, iy1), 0.0f);
    float inter = __fmul_rn(iw, ih);
    float uni = __fsub_rn(__fadd_rn(areaA, areaB), inter);
    bool sup = (uni > 0.0f) && (__fdiv_rn(inter, uni) > 0.7f);
    bits |= ((uint64_t)sup) << c;
  }
  maskT[(size_t)bx * ROWS + i] = bits;   // lanes contiguous -> 512B coalesced
}

// wave-uniform 64-bit broadcast via v_readlane
__device__ __forceinline__ uint64_t bcast64(uint64_t v, int lane) {
  uint32_t lo = (uint32_t)__builtin_amdgcn_readlane((int)(uint32_t)v, lane);
  uint32_t hi = (uint32_t)__builtin_amdgcn_readlane((int)(uint32_t)(v >> 32), lane);
  return ((uint64_t)hi << 32) | lo;
}

// select-OR 64 contiguous rows' words by keptmask (32 independent 16B loads)
__device__ __forceinline__ uint64_t fold_sel(const uint64_t* rowbase, uint64_t keptmask) {
  const ulonglong2* p = (const ulonglong2*)rowbase;
  uint64_t acc = 0;
  #pragma unroll
  for (int rr = 0; rr < 32; rr++) {
    ulonglong2 m2 = p[rr];
    acc |= (m2.x & (0ull - ((keptmask >> (2 * rr)) & 1ull)));
    acc |= (m2.y & (0ull - ((keptmask >> (2 * rr + 1)) & 1ull)));
  }
  return acc;
}

// ---- K6: sequential NMS scan, single wave, pipelined fold ----
__global__ void __launch_bounds__(64) k_nms(const uint64_t* __restrict__ maskT,
                                            const float4* __restrict__ boxes,
                                            const uint32_t* __restrict__ valid,
                                            float* __restrict__ out) {
  __shared__ uint32_t list[POST_K];
  int lane = threadIdx.x;
  int w0 = lane, w1 = lane + 64;
  uint64_t r0 = 0, r1 = 0;   // removed-bit words: lane owns words w0, w1
  int cnt = 0;
  for (int g = 0; g < WORDS && cnt < POST_K; g++) {
    int base = g * 64;
    uint64_t cur = (g < 64) ? bcast64(r0, g) : bcast64(r1, g - 64);
    uint64_t colv = maskT[(size_t)g * ROWS + base + lane];
    uint32_t vf = valid[base + lane];
    uint64_t vmask = __ballot(vf != 0u);
    uint64_t alive = vmask & ~cur;
    uint64_t keptmask = 0;
    while (alive) {
      int r = __ffsll((unsigned long long)alive) - 1;
      keptmask |= 1ull << r;
      if (lane == 0) list[cnt] = (uint32_t)(base + r);
      cnt++;
      if (cnt >= POST_K) break;
      uint64_t m = bcast64(colv, r);
      alive &= ~m;
      alive &= ~(1ull << r);
    }
    if (keptmask && cnt < POST_K) {
      if (w0 > g)
        r0 |= fold_sel(maskT + (size_t)w0 * ROWS + base, keptmask);
      if (w1 > g && w1 < WORDS)
        r1 |= fold_sel(maskT + (size_t)w1 * ROWS + base, keptmask);
    }
  }
  __syncthreads();
  float4* outv = (float4*)out;
  for (int k = lane; k < cnt; k += 64)
    outv[k] = boxes[list[k]];
}

extern "C" void kernel_launch(void* const* d_in, const int* in_sizes, int n_in,
                              void* d_out, int out_size, void* d_ws, size_t ws_size,
                              hipStream_t stream) {
  const float4* anchors = (const float4*)d_in[1];
  const float4* deltas  = (const float4*)d_in[2];
  const float*  logits  = (const float*)d_in[3];
  char* w = (char*)d_ws;
  uint32_t* keys  = (uint32_t*)(w + OFF_KEYS);
  uint32_t* part1 = (uint32_t*)(w + OFF_PART1);
  uint32_t* part2 = (uint32_t*)(w + OFF_PART2);
  uint32_t* ctrl  = (uint32_t*)(w + OFF_CTRL);
  uint64_t* cand  = (uint64_t*)(w + OFF_CAND);
  float4*   boxes = (float4*)(w + OFF_BOXES);
  uint32_t* valid = (uint32_t*)(w + OFF_VALID);
  uint64_t* maskT = (uint64_t*)(w + OFF_MASK);
  float*    out   = (float*)d_out;

  hipMemsetAsync(w + OFF_CTRL, 0, 256, stream);
  hipMemsetAsync(d_out, 0, (size_t)out_size * sizeof(float), stream);

  k_score<<<NBLK1, 1024, 0, stream>>>(anchors, deltas, logits, keys, part1);
  k_findcut1<<<1, 1024, 0, stream>>>(part1, ctrl);
  k_hist2<<<NBLK1, 1024, 0, stream>>>(keys, ctrl, part2);
  k_findcut2<<<1, 256, 0, stream>>>(part2, ctrl);
  k_compact<<<(N_ANCH + 255) / 256, 256, 0, stream>>>(keys, ctrl, &ctrl[0], cand);
  k_sort<<<1, 1024, 0, stream>>>(ctrl, cand);
  k_gather<<<(ROWS + 255) / 256, 256, 0, stream>>>(cand, anchors, deltas, boxes, valid);
  k_iou<<<dim3(WORDS, WORDS), 64, 0, stream>>>(boxes, maskT);
  k_nms<<<1, 64, 0, stream>>>(maskT, boxes, valid, out);
}